// Round 8
// baseline (1457.967 us; speedup 1.0000x reference)
//
#include <hip/hip_runtime.h>
#include <hip/hip_bf16.h>

typedef unsigned short u16;
typedef __attribute__((ext_vector_type(8))) short short8;
typedef __attribute__((ext_vector_type(4))) short short4v;
typedef __attribute__((ext_vector_type(4))) float f32x4;
typedef __attribute__((ext_vector_type(16))) float f32x16;

__device__ __forceinline__ u16 f2bf(float f){
  __hip_bfloat16 h = __float2bfloat16(f);
  return *reinterpret_cast<u16*>(&h);
}

// fast GELU: tanh form computed as u * sigmoid(2y). Validated r1-r7:
// absmax unchanged (0.03125), bf16 rounding dominates.
__device__ __forceinline__ float gelu_fast(float u){
  float uu = u * u;
  float e = __expf(u * fmaf(uu, -0.0713548163f, -1.5957691216f));
  return u * __builtin_amdgcn_rcpf(1.f + e);
}

// ---------------- weight transpose+convert: W f32 (KxN) -> Wt bf16 (NxK) ----
__global__ void transpose_all(const float* __restrict__ w0, u16* __restrict__ d0,   // 192x576
                              const float* __restrict__ w1, u16* __restrict__ d1,   // 192x192
                              const float* __restrict__ w2, u16* __restrict__ d2,   // 192x768
                              const float* __restrict__ w3, u16* __restrict__ d3)   // 768x192
{
  int seg = blockIdx.y;
  const float* s; u16* d; int K, N;
  if      (seg == 0){ s = w0; d = d0; K = 192; N = 576; }
  else if (seg == 1){ s = w1; d = d1; K = 192; N = 192; }
  else if (seg == 2){ s = w2; d = d2; K = 192; N = 768; }
  else              { s = w3; d = d3; K = 768; N = 192; }
  int idx = blockIdx.x * 256 + threadIdx.x;
  if (idx < K * N){
    int k = idx / N, n = idx % N;
    d[n * K + k] = f2bf(s[idx]);
  }
}

// ---------------- K1: fused LN1 + QKV + window attention + proj + residual
// One block per 8x8 window (4096 blocks, 256 threads = 4 waves).
// r6-EXACT (best measured ~385us): stride-200 LDS, direct global->LDS staging.
__global__ __launch_bounds__(256, 2) void win_attn(
    const float* __restrict__ x,  const float* __restrict__ g1, const float* __restrict__ b1,
    const u16* __restrict__ wqkvT, const float* __restrict__ bqkv,
    const u16* __restrict__ wprojT, const float* __restrict__ bproj,
    float* __restrict__ out)
{
  __shared__ u16 hw[64 * 200];    // LN1'd window tokens, bf16 (rows wave-private)
  __shared__ u16 wch[96 * 200];   // per-head qkv weight chunk; later aliased:
  u16* Ql = wch;                  // 64 x 40
  u16* Kl = wch + 64 * 40;        // 64 x 40
  u16* Vt = Kl  + 64 * 40;        // 32 x 72 (V transposed: [ch][token])
  u16* Pl = Vt  + 32 * 72;        // 64 x 72 (P, rows wave-private)

  const int tid = threadIdx.x, lane = tid & 63, w = tid >> 6;
  const int l15 = lane & 15, quad = lane >> 4;
  const int wid = blockIdx.x;
  const int b = wid >> 10, hy = (wid >> 5) & 31, wx = wid & 31;

  // ---- LN1 into hw: 4 lanes per token, 16 tokens per wave ----
  {
    int n = w * 16 + (lane >> 2), p = lane & 3;
    int hr = hy * 8 + (n >> 3), wcc = wx * 8 + (n & 7);
    size_t tg = ((size_t)(b * 256 + hr)) * 256 + wcc;
    const float* xr = x + tg * 192 + p * 48;
    float v[48];
    #pragma unroll
    for (int c = 0; c < 12; c++) *(float4*)(v + c * 4) = *(const float4*)(xr + c * 4);
    float s = 0.f, ss = 0.f;
    #pragma unroll
    for (int i = 0; i < 48; i++){ s += v[i]; ss += v[i] * v[i]; }
    s += __shfl_xor(s, 1); ss += __shfl_xor(ss, 1);
    s += __shfl_xor(s, 2); ss += __shfl_xor(ss, 2);
    float m  = s * (1.f / 192.f);
    float rs = rsqrtf(ss * (1.f / 192.f) - m * m + 1e-5f);
    #pragma unroll
    for (int c = 0; c < 12; c++){
      float4 gv = *(const float4*)(g1 + p * 48 + c * 4);
      float4 bv = *(const float4*)(b1 + p * 48 + c * 4);
      short4v t;
      t.x = (short)f2bf((v[c*4+0] - m) * rs * gv.x + bv.x);
      t.y = (short)f2bf((v[c*4+1] - m) * rs * gv.y + bv.y);
      t.z = (short)f2bf((v[c*4+2] - m) * rs * gv.z + bv.z);
      t.w = (short)f2bf((v[c*4+3] - m) * rs * gv.w + bv.w);
      *(short4v*)&hw[n * 200 + p * 48 + c * 4] = t;
    }
  }

  const int qrow = w * 16 + quad * 4;   // +r gives this lane's C-layout rows
  f32x4 oall[6][2];
  #pragma unroll
  for (int h = 0; h < 6; h++)
    #pragma unroll
    for (int nt = 0; nt < 2; nt++) oall[h][nt] = (f32x4){0.f, 0.f, 0.f, 0.f};

  #pragma unroll
  for (int head = 0; head < 6; ++head){
    __syncthreads();   // protect wch region (Kl/Vt/Pl) from previous head's readers
    // stage this head's 96x192 slice of wqkvT (rows: q,k,v blocks), bf16
    #pragma unroll
    for (int it = 0; it < 9; ++it){
      int c = tid + it * 256;
      int row = c / 24, cc = c % 24;
      int gr = (row >> 5) * 192 + head * 32 + (row & 31);
      *(uint4*)&wch[row * 200 + cc * 8] = *(const uint4*)(wqkvT + (size_t)gr * 192 + cc * 8);
    }
    __syncthreads();
    // QKV: wave's 16 token rows x 32 cols per matrix, K=192
    f32x4 acc[3][2];
    #pragma unroll
    for (int mat = 0; mat < 3; mat++)
      #pragma unroll
      for (int nt = 0; nt < 2; nt++) acc[mat][nt] = (f32x4){0.f, 0.f, 0.f, 0.f};
    #pragma unroll
    for (int k = 0; k < 6; k++){
      short8 af = *(const short8*)&hw[(w * 16 + l15) * 200 + k * 32 + quad * 8];
      #pragma unroll
      for (int mat = 0; mat < 3; mat++)
        #pragma unroll
        for (int nt = 0; nt < 2; nt++){
          short8 bfv = *(const short8*)&wch[(mat * 32 + nt * 16 + l15) * 200 + k * 32 + quad * 8];
          acc[mat][nt] = __builtin_amdgcn_mfma_f32_16x16x32_bf16(af, bfv, acc[mat][nt], 0, 0, 0);
        }
    }
    __syncthreads();   // all waves done reading wch before aliased writes
    #pragma unroll
    for (int nt = 0; nt < 2; nt++){
      float bq = bqkv[      head * 32 + nt * 16 + l15];
      float bk = bqkv[192 + head * 32 + nt * 16 + l15];
      float bv = bqkv[384 + head * 32 + nt * 16 + l15];
      #pragma unroll
      for (int r = 0; r < 4; r++){
        Ql[(qrow + r) * 40 + nt * 16 + l15] = f2bf(acc[0][nt][r] + bq);
        Kl[(qrow + r) * 40 + nt * 16 + l15] = f2bf(acc[1][nt][r] + bk);
        Vt[(nt * 16 + l15) * 72 + qrow + r] = f2bf(acc[2][nt][r] + bv);
      }
    }
    __syncthreads();   // Kl/Vt are cross-wave
    // S = Q K^T : hd=32 == one 16x16x32 MFMA k-step
    short8 aq = *(const short8*)&Ql[(w * 16 + l15) * 40 + quad * 8];
    f32x4 sa[4];
    #pragma unroll
    for (int kt = 0; kt < 4; kt++){
      short8 bk8 = *(const short8*)&Kl[(kt * 16 + l15) * 40 + quad * 8];
      sa[kt] = __builtin_amdgcn_mfma_f32_16x16x32_bf16(aq, bk8, (f32x4){0.f,0.f,0.f,0.f}, 0, 0, 0);
    }
    const float scale = 0.17677669529663687f;  // 32^-0.5
    float inv[4];
    #pragma unroll
    for (int r = 0; r < 4; r++){
      float s0 = sa[0][r] * scale, s1 = sa[1][r] * scale;
      float s2 = sa[2][r] * scale, s3 = sa[3][r] * scale;
      float mx = fmaxf(fmaxf(s0, s1), fmaxf(s2, s3));
      mx = fmaxf(mx, __shfl_xor(mx, 1)); mx = fmaxf(mx, __shfl_xor(mx, 2));
      mx = fmaxf(mx, __shfl_xor(mx, 4)); mx = fmaxf(mx, __shfl_xor(mx, 8));
      float p0 = __expf(s0 - mx), p1 = __expf(s1 - mx);
      float p2 = __expf(s2 - mx), p3 = __expf(s3 - mx);
      float l = p0 + p1 + p2 + p3;
      l += __shfl_xor(l, 1); l += __shfl_xor(l, 2);
      l += __shfl_xor(l, 4); l += __shfl_xor(l, 8);
      inv[r] = 1.f / l;
      Pl[(qrow + r) * 72 +      l15] = f2bf(p0);
      Pl[(qrow + r) * 72 + 16 + l15] = f2bf(p1);
      Pl[(qrow + r) * 72 + 32 + l15] = f2bf(p2);
      Pl[(qrow + r) * 72 + 48 + l15] = f2bf(p3);
    }
    // O = P V  (Pl rows wave-private; Vt barrier already passed)
    f32x4 oa[2];
    oa[0] = (f32x4){0.f,0.f,0.f,0.f}; oa[1] = (f32x4){0.f,0.f,0.f,0.f};
    #pragma unroll
    for (int ks = 0; ks < 2; ks++){
      short8 ap = *(const short8*)&Pl[(w * 16 + l15) * 72 + ks * 32 + quad * 8];
      #pragma unroll
      for (int nt = 0; nt < 2; nt++){
        short8 bv8 = *(const short8*)&Vt[(nt * 16 + l15) * 72 + ks * 32 + quad * 8];
        oa[nt] = __builtin_amdgcn_mfma_f32_16x16x32_bf16(ap, bv8, oa[nt], 0, 0, 0);
      }
    }
    #pragma unroll
    for (int nt = 0; nt < 2; nt++)
      #pragma unroll
      for (int r = 0; r < 4; r++)
        oall[head][nt][r] = oa[nt][r] * inv[r];
  }

  // stash O (64x192, bf16) into hw (rows wave-private; hw's LN content is dead)
  #pragma unroll
  for (int h = 0; h < 6; h++)
    #pragma unroll
    for (int nt = 0; nt < 2; nt++)
      #pragma unroll
      for (int r = 0; r < 4; r++)
        hw[(qrow + r) * 200 + h * 32 + nt * 16 + l15] = f2bf(oall[h][nt][r]);

  // proj: xo = x + O @ w_proj + b_proj  (B-frags streamed from L2-resident wprojT)
  f32x4 accP[12];
  #pragma unroll
  for (int nt = 0; nt < 12; nt++) accP[nt] = (f32x4){0.f,0.f,0.f,0.f};
  #pragma unroll
  for (int k = 0; k < 6; k++){
    short8 af = *(const short8*)&hw[(w * 16 + l15) * 200 + k * 32 + quad * 8];
    #pragma unroll
    for (int nt = 0; nt < 12; nt++){
      short8 bfv = *(const short8*)(wprojT + (size_t)(nt * 16 + l15) * 192 + k * 32 + quad * 8);
      accP[nt] = __builtin_amdgcn_mfma_f32_16x16x32_bf16(af, bfv, accP[nt], 0, 0, 0);
    }
  }
  #pragma unroll
  for (int r = 0; r < 4; r++){
    int nn = qrow + r;
    int hr = hy * 8 + (nn >> 3), wcc = wx * 8 + (nn & 7);
    size_t tg = ((size_t)(b * 256 + hr)) * 256 + wcc;
    #pragma unroll
    for (int nt = 0; nt < 12; nt++){
      int col = nt * 16 + l15;
      size_t idx = tg * 192 + col;
      out[idx] = accP[nt][r] + bproj[col] + x[idx];
    }
  }
}

// ---------------- K2: fused LN2 + fc1 + GELU + fc2 + residual (in-place on io)
// v8: 32x32x16 MFMA math (v7-validated layouts) AT 2 blocks/CU:
//  - fc1 A-fragments in regs (12x short8, loaded once) -> h2t dead early,
//    ALIASED with w2b staging buffer -> LDS 61 KB.
//  - v4-style reg staging (12 uint4/thread), raw s_barrier + lgkmcnt only
//    (no __syncthreads vmcnt(0) drain) so prefetch flies across barriers.
// Chunk = 64 fc1-cols, 12 chunks, 3 barriers/chunk.
__global__ __launch_bounds__(256) void mlp_fused(
    const float* __restrict__ g2, const float* __restrict__ b2,
    const u16* __restrict__ wfc1T, const float* __restrict__ bfc1,
    const u16* __restrict__ wfc2T, const float* __restrict__ bfc2,
    float* __restrict__ io)
{
  __shared__ u16 w2b[192 * 72];   // 27.6 KB fc2 chunk [outcol][kk]; FIRST used as h2t [64][200]
  __shared__ u16 w1b[64 * 200];   // 25.6 KB fc1 chunk [fc1col][k]
  __shared__ u16 Ut [64 * 72];    //  9.2 KB gelu(U) [tok][kk]
  u16* h2t = w2b;                 // transient alias (dead before first w2 commit)

  const int tid = threadIdx.x, lane = tid & 63, w = tid >> 6;
  const int wm = w >> 1, wn = w & 1;          // token half / col half
  const int l31 = lane & 31, half = lane >> 5;
  const int t0 = blockIdx.x * 64;

  // staging prefetch regs: w1 chunk 64x192 u16 (1536 uint4) + w2 192x64 (1536)
  uint4 p1[6], p2[6];

  #define ISSUE(ch)                                                                        \
    { _Pragma("unroll")                                                                    \
      for (int it = 0; it < 6; ++it){                                                      \
        int c = tid + it * 256;                                                            \
        p1[it] = *(const uint4*)(wfc1T + (size_t)((ch) * 64 + c / 24) * 192 + (c % 24) * 8);\
        p2[it] = *(const uint4*)(wfc2T + (size_t)(c >> 3) * 768 + (ch) * 64 + (c & 7) * 8); \
      } }
  #define COMMIT()                                                                         \
    { _Pragma("unroll")                                                                    \
      for (int it = 0; it < 6; ++it){                                                      \
        int c = tid + it * 256;                                                            \
        *(uint4*)&w1b[(c / 24) * 200 + (c % 24) * 8] = p1[it];                             \
        *(uint4*)&w2b[(c >> 3) * 72 + (c & 7) * 8] = p2[it];                               \
      } }

  ISSUE(0);   // chunk-0 loads fly under LN

  // ---- LN2 into h2t (in w2b region) ----
  {
    int n = w * 16 + (lane >> 2), p = lane & 3;
    const float* xr = io + (size_t)(t0 + n) * 192 + p * 48;
    float v[48];
    #pragma unroll
    for (int c = 0; c < 12; c++) *(float4*)(v + c * 4) = *(const float4*)(xr + c * 4);
    float s = 0.f, ss = 0.f;
    #pragma unroll
    for (int i = 0; i < 48; i++){ s += v[i]; ss += v[i] * v[i]; }
    s += __shfl_xor(s, 1); ss += __shfl_xor(ss, 1);
    s += __shfl_xor(s, 2); ss += __shfl_xor(ss, 2);
    float m  = s * (1.f / 192.f);
    float rs = rsqrtf(ss * (1.f / 192.f) - m * m + 1e-5f);
    #pragma unroll
    for (int c = 0; c < 12; c++){
      float4 gv = *(const float4*)(g2 + p * 48 + c * 4);
      float4 bv = *(const float4*)(b2 + p * 48 + c * 4);
      short4v t;
      t.x = (short)f2bf((v[c*4+0] - m) * rs * gv.x + bv.x);
      t.y = (short)f2bf((v[c*4+1] - m) * rs * gv.y + bv.y);
      t.z = (short)f2bf((v[c*4+2] - m) * rs * gv.z + bv.z);
      t.w = (short)f2bf((v[c*4+3] - m) * rs * gv.w + bv.w);
      *(short4v*)&h2t[n * 200 + p * 48 + c * 4] = t;
    }
  }
  asm volatile("s_waitcnt lgkmcnt(0)" ::: "memory");
  __builtin_amdgcn_s_barrier();               // h2t visible to all waves

  // ---- fc1 A-fragments to regs (rows wm*32+l31, k = ks*16+half*8) ----
  short8 afr[12];
  #pragma unroll
  for (int ks = 0; ks < 12; ++ks)
    afr[ks] = *(const short8*)&h2t[(wm * 32 + l31) * 200 + ks * 16 + half * 8];
  asm volatile("s_waitcnt lgkmcnt(0)" ::: "memory");
  __builtin_amdgcn_s_barrier();               // h2t dead; w2b region reusable

  f32x16 accO[3];
  #pragma unroll
  for (int t = 0; t < 3; ++t)
    #pragma unroll
    for (int i = 0; i < 16; ++i) accO[t][i] = 0.f;

  for (int ch = 0; ch < 12; ++ch){
    COMMIT();                                 // waits p1/p2 (compiler vmcnt), ds_writes
    if (ch < 11) ISSUE(ch + 1);               // next chunk flies across barriers
    float bb = bfc1[ch * 64 + wn * 32 + l31]; // L2-hit, hidden under fc1
    asm volatile("s_waitcnt lgkmcnt(0)" ::: "memory");
    __builtin_amdgcn_s_barrier();             // staged chunk visible

    // fc1: [32 tok x 32 cols], K=192 (12 k-steps, A from regs)
    f32x16 au;
    #pragma unroll
    for (int i = 0; i < 16; ++i) au[i] = 0.f;
    #pragma unroll
    for (int ks = 0; ks < 12; ++ks){
      short8 bf = *(const short8*)&w1b[(wn * 32 + l31) * 200 + ks * 16 + half * 8];
      au = __builtin_amdgcn_mfma_f32_32x32x16_bf16(afr[ks], bf, au, 0, 0, 0);
    }
    // bias + GELU -> Ut  (C layout: col=l31=fc1col, tokrow=(r&3)+8*(r>>2)+4*half)
    #pragma unroll
    for (int r = 0; r < 16; ++r){
      int tr = (r & 3) + 8 * (r >> 2) + 4 * half;
      Ut[(wm * 32 + tr) * 72 + wn * 32 + l31] = f2bf(gelu_fast(au[r] + bb));
    }
    asm volatile("s_waitcnt lgkmcnt(0)" ::: "memory");
    __builtin_amdgcn_s_barrier();             // Ut visible (cross-wn); w1b reads done

    // fc2: [32 tok x 96 outcols], K=64 (4 k-steps x 3 col-tiles)
    #pragma unroll
    for (int ks = 0; ks < 4; ++ks){
      short8 uf = *(const short8*)&Ut[(wm * 32 + l31) * 72 + ks * 16 + half * 8];
      #pragma unroll
      for (int t = 0; t < 3; ++t){
        short8 bf = *(const short8*)&w2b[(wn * 96 + t * 32 + l31) * 72 + ks * 16 + half * 8];
        accO[t] = __builtin_amdgcn_mfma_f32_32x32x16_bf16(uf, bf, accO[t], 0, 0, 0);
      }
    }
    asm volatile("s_waitcnt lgkmcnt(0)" ::: "memory");
    __builtin_amdgcn_s_barrier();             // w2b/Ut reads retired before next COMMIT
  }

  // epilogue: out = xo + (accO + b_fc2), in place (block-disjoint rows)
  #pragma unroll
  for (int t = 0; t < 3; ++t){
    int col = wn * 96 + t * 32 + l31;
    float bbo = bfc2[col];
    #pragma unroll
    for (int r = 0; r < 16; ++r){
      int row = t0 + wm * 32 + (r & 3) + 8 * (r >> 2) + 4 * half;
      size_t idx = (size_t)row * 192 + col;
      io[idx] = accO[t][r] + bbo + io[idx];
    }
  }
  #undef ISSUE
  #undef COMMIT
}

// ------------------------------------------------------------------------
extern "C" void kernel_launch(void* const* d_in, const int* in_sizes, int n_in,
                              void* d_out, int out_size, void* d_ws, size_t ws_size,
                              hipStream_t stream) {
  const float* x      = (const float*)d_in[0];
  const float* g1     = (const float*)d_in[1];
  const float* b1     = (const float*)d_in[2];
  const float* w_qkv  = (const float*)d_in[3];
  const float* b_qkv  = (const float*)d_in[4];
  const float* w_proj = (const float*)d_in[5];
  const float* b_proj = (const float*)d_in[6];
  const float* g2     = (const float*)d_in[7];
  const float* b2     = (const float*)d_in[8];
  const float* w_fc1  = (const float*)d_in[9];
  const float* b_fc1  = (const float*)d_in[10];
  const float* w_fc2  = (const float*)d_in[11];
  const float* b_fc2  = (const float*)d_in[12];
  float* out = (float*)d_out;

  // workspace: transposed bf16 weights only (<1 MB)
  u16* wqkvT  = (u16*)d_ws;                      // 576x192
  u16* wprojT = wqkvT  + 576 * 192;              // 192x192
  u16* wfc1T  = wprojT + 192 * 192;              // 768x192
  u16* wfc2T  = wfc1T  + 768 * 192;              // 192x768

  transpose_all<<<dim3(576, 4), 256, 0, stream>>>(w_qkv, wqkvT, w_proj, wprojT,
                                                  w_fc1, wfc1T, w_fc2, wfc2T);
  // d_out = x + attn(LN1(x)) @ w_proj + b_proj   (window-fused)
  win_attn<<<4096, 256, 0, stream>>>(x, g1, b1, wqkvT, b_qkv, wprojT, b_proj, out);
  // d_out += gelu(LN2(d_out) @ w_fc1 + b_fc1) @ w_fc2 + b_fc2   (in place)
  mlp_fused<<<4096, 256, 0, stream>>>(g2, b2, wfc1T, b_fc1, wfc2T, b_fc2, out);
}

// Round 9
// 905.404 us; speedup vs baseline: 1.6103x; 1.6103x over previous
//
#include <hip/hip_runtime.h>
#include <hip/hip_bf16.h>

typedef unsigned short u16;
typedef __attribute__((ext_vector_type(8))) short short8;
typedef __attribute__((ext_vector_type(4))) short short4v;
typedef __attribute__((ext_vector_type(4))) float f32x4;
typedef __attribute__((ext_vector_type(16))) float f32x16;

__device__ __forceinline__ u16 f2bf(float f){
  __hip_bfloat16 h = __float2bfloat16(f);
  return *reinterpret_cast<u16*>(&h);
}

// fast GELU: tanh form computed as u * sigmoid(2y). Validated r1-r8:
// absmax unchanged (0.03125), bf16 rounding dominates.
__device__ __forceinline__ float gelu_fast(float u){
  float uu = u * u;
  float e = __expf(u * fmaf(uu, -0.0713548163f, -1.5957691216f));
  return u * __builtin_amdgcn_rcpf(1.f + e);
}

// ---------------- weight transpose+convert ----------------
// d0: wqkvT  [576][192]            (win_attn)
// d1: wprojT [192][192]            (win_attn)
// d2: wfc1P  [12 chunks][64][200]  chunk-contiguous, 25600 B = 25 x 1KB  (v7-proven)
// d3: wfc2P  [12 chunks][192][72]  chunk-contiguous, 27648 B = 27 x 1KB  (v7-proven)
__global__ void transpose_all(const float* __restrict__ w0, u16* __restrict__ d0,   // 192x576
                              const float* __restrict__ w1, u16* __restrict__ d1,   // 192x192
                              const float* __restrict__ w2, u16* __restrict__ d2,   // 192x768
                              const float* __restrict__ w3, u16* __restrict__ d3)   // 768x192
{
  int seg = blockIdx.y;
  int idx = blockIdx.x * 256 + threadIdx.x;
  if (seg == 0){
    if (idx < 192 * 576){ int k = idx / 576, n = idx % 576; d0[n * 192 + k] = f2bf(w0[idx]); }
  } else if (seg == 1){
    if (idx < 192 * 192){ int k = idx / 192, n = idx % 192; d1[n * 192 + k] = f2bf(w1[idx]); }
  } else if (seg == 2){
    if (idx < 192 * 768){
      int k = idx / 768, n = idx % 768;
      d2[(size_t)(n >> 6) * 12800 + (n & 63) * 200 + k] = f2bf(w2[idx]);
    }
  } else {
    if (idx < 768 * 192){
      int k = idx / 192, n = idx % 192;
      d3[(size_t)(k >> 6) * 13824 + n * 72 + (k & 63)] = f2bf(w3[idx]);
    }
  }
}

// ---------------- K1: fused LN1 + QKV + window attention + proj + residual
// One block per 8x8 window (4096 blocks, 256 threads = 4 waves).
// r6-EXACT (best measured ~385us): stride-200 LDS, direct global->LDS staging.
__global__ __launch_bounds__(256, 2) void win_attn(
    const float* __restrict__ x,  const float* __restrict__ g1, const float* __restrict__ b1,
    const u16* __restrict__ wqkvT, const float* __restrict__ bqkv,
    const u16* __restrict__ wprojT, const float* __restrict__ bproj,
    float* __restrict__ out)
{
  __shared__ u16 hw[64 * 200];    // LN1'd window tokens, bf16 (rows wave-private)
  __shared__ u16 wch[96 * 200];   // per-head qkv weight chunk; later aliased:
  u16* Ql = wch;                  // 64 x 40
  u16* Kl = wch + 64 * 40;        // 64 x 40
  u16* Vt = Kl  + 64 * 40;        // 32 x 72 (V transposed: [ch][token])
  u16* Pl = Vt  + 32 * 72;        // 64 x 72 (P, rows wave-private)

  const int tid = threadIdx.x, lane = tid & 63, w = tid >> 6;
  const int l15 = lane & 15, quad = lane >> 4;
  const int wid = blockIdx.x;
  const int b = wid >> 10, hy = (wid >> 5) & 31, wx = wid & 31;

  // ---- LN1 into hw: 4 lanes per token, 16 tokens per wave ----
  {
    int n = w * 16 + (lane >> 2), p = lane & 3;
    int hr = hy * 8 + (n >> 3), wcc = wx * 8 + (n & 7);
    size_t tg = ((size_t)(b * 256 + hr)) * 256 + wcc;
    const float* xr = x + tg * 192 + p * 48;
    float v[48];
    #pragma unroll
    for (int c = 0; c < 12; c++) *(float4*)(v + c * 4) = *(const float4*)(xr + c * 4);
    float s = 0.f, ss = 0.f;
    #pragma unroll
    for (int i = 0; i < 48; i++){ s += v[i]; ss += v[i] * v[i]; }
    s += __shfl_xor(s, 1); ss += __shfl_xor(ss, 1);
    s += __shfl_xor(s, 2); ss += __shfl_xor(ss, 2);
    float m  = s * (1.f / 192.f);
    float rs = rsqrtf(ss * (1.f / 192.f) - m * m + 1e-5f);
    #pragma unroll
    for (int c = 0; c < 12; c++){
      float4 gv = *(const float4*)(g1 + p * 48 + c * 4);
      float4 bv = *(const float4*)(b1 + p * 48 + c * 4);
      short4v t;
      t.x = (short)f2bf((v[c*4+0] - m) * rs * gv.x + bv.x);
      t.y = (short)f2bf((v[c*4+1] - m) * rs * gv.y + bv.y);
      t.z = (short)f2bf((v[c*4+2] - m) * rs * gv.z + bv.z);
      t.w = (short)f2bf((v[c*4+3] - m) * rs * gv.w + bv.w);
      *(short4v*)&hw[n * 200 + p * 48 + c * 4] = t;
    }
  }

  const int qrow = w * 16 + quad * 4;   // +r gives this lane's C-layout rows
  f32x4 oall[6][2];
  #pragma unroll
  for (int h = 0; h < 6; h++)
    #pragma unroll
    for (int nt = 0; nt < 2; nt++) oall[h][nt] = (f32x4){0.f, 0.f, 0.f, 0.f};

  #pragma unroll
  for (int head = 0; head < 6; ++head){
    __syncthreads();   // protect wch region (Kl/Vt/Pl) from previous head's readers
    // stage this head's 96x192 slice of wqkvT (rows: q,k,v blocks), bf16
    #pragma unroll
    for (int it = 0; it < 9; ++it){
      int c = tid + it * 256;
      int row = c / 24, cc = c % 24;
      int gr = (row >> 5) * 192 + head * 32 + (row & 31);
      *(uint4*)&wch[row * 200 + cc * 8] = *(const uint4*)(wqkvT + (size_t)gr * 192 + cc * 8);
    }
    __syncthreads();
    // QKV: wave's 16 token rows x 32 cols per matrix, K=192
    f32x4 acc[3][2];
    #pragma unroll
    for (int mat = 0; mat < 3; mat++)
      #pragma unroll
      for (int nt = 0; nt < 2; nt++) acc[mat][nt] = (f32x4){0.f, 0.f, 0.f, 0.f};
    #pragma unroll
    for (int k = 0; k < 6; k++){
      short8 af = *(const short8*)&hw[(w * 16 + l15) * 200 + k * 32 + quad * 8];
      #pragma unroll
      for (int mat = 0; mat < 3; mat++)
        #pragma unroll
        for (int nt = 0; nt < 2; nt++){
          short8 bfv = *(const short8*)&wch[(mat * 32 + nt * 16 + l15) * 200 + k * 32 + quad * 8];
          acc[mat][nt] = __builtin_amdgcn_mfma_f32_16x16x32_bf16(af, bfv, acc[mat][nt], 0, 0, 0);
        }
    }
    __syncthreads();   // all waves done reading wch before aliased writes
    #pragma unroll
    for (int nt = 0; nt < 2; nt++){
      float bq = bqkv[      head * 32 + nt * 16 + l15];
      float bk = bqkv[192 + head * 32 + nt * 16 + l15];
      float bv = bqkv[384 + head * 32 + nt * 16 + l15];
      #pragma unroll
      for (int r = 0; r < 4; r++){
        Ql[(qrow + r) * 40 + nt * 16 + l15] = f2bf(acc[0][nt][r] + bq);
        Kl[(qrow + r) * 40 + nt * 16 + l15] = f2bf(acc[1][nt][r] + bk);
        Vt[(nt * 16 + l15) * 72 + qrow + r] = f2bf(acc[2][nt][r] + bv);
      }
    }
    __syncthreads();   // Kl/Vt are cross-wave
    // S = Q K^T : hd=32 == one 16x16x32 MFMA k-step
    short8 aq = *(const short8*)&Ql[(w * 16 + l15) * 40 + quad * 8];
    f32x4 sa[4];
    #pragma unroll
    for (int kt = 0; kt < 4; kt++){
      short8 bk8 = *(const short8*)&Kl[(kt * 16 + l15) * 40 + quad * 8];
      sa[kt] = __builtin_amdgcn_mfma_f32_16x16x32_bf16(aq, bk8, (f32x4){0.f,0.f,0.f,0.f}, 0, 0, 0);
    }
    const float scale = 0.17677669529663687f;  // 32^-0.5
    float inv[4];
    #pragma unroll
    for (int r = 0; r < 4; r++){
      float s0 = sa[0][r] * scale, s1 = sa[1][r] * scale;
      float s2 = sa[2][r] * scale, s3 = sa[3][r] * scale;
      float mx = fmaxf(fmaxf(s0, s1), fmaxf(s2, s3));
      mx = fmaxf(mx, __shfl_xor(mx, 1)); mx = fmaxf(mx, __shfl_xor(mx, 2));
      mx = fmaxf(mx, __shfl_xor(mx, 4)); mx = fmaxf(mx, __shfl_xor(mx, 8));
      float p0 = __expf(s0 - mx), p1 = __expf(s1 - mx);
      float p2 = __expf(s2 - mx), p3 = __expf(s3 - mx);
      float l = p0 + p1 + p2 + p3;
      l += __shfl_xor(l, 1); l += __shfl_xor(l, 2);
      l += __shfl_xor(l, 4); l += __shfl_xor(l, 8);
      inv[r] = 1.f / l;
      Pl[(qrow + r) * 72 +      l15] = f2bf(p0);
      Pl[(qrow + r) * 72 + 16 + l15] = f2bf(p1);
      Pl[(qrow + r) * 72 + 32 + l15] = f2bf(p2);
      Pl[(qrow + r) * 72 + 48 + l15] = f2bf(p3);
    }
    // O = P V  (Pl rows wave-private; Vt barrier already passed)
    f32x4 oa[2];
    oa[0] = (f32x4){0.f,0.f,0.f,0.f}; oa[1] = (f32x4){0.f,0.f,0.f,0.f};
    #pragma unroll
    for (int ks = 0; ks < 2; ks++){
      short8 ap = *(const short8*)&Pl[(w * 16 + l15) * 72 + ks * 32 + quad * 8];
      #pragma unroll
      for (int nt = 0; nt < 2; nt++){
        short8 bv8 = *(const short8*)&Vt[(nt * 16 + l15) * 72 + ks * 32 + quad * 8];
        oa[nt] = __builtin_amdgcn_mfma_f32_16x16x32_bf16(ap, bv8, oa[nt], 0, 0, 0);
      }
    }
    #pragma unroll
    for (int nt = 0; nt < 2; nt++)
      #pragma unroll
      for (int r = 0; r < 4; r++)
        oall[head][nt][r] = oa[nt][r] * inv[r];
  }

  // stash O (64x192, bf16) into hw (rows wave-private; hw's LN content is dead)
  #pragma unroll
  for (int h = 0; h < 6; h++)
    #pragma unroll
    for (int nt = 0; nt < 2; nt++)
      #pragma unroll
      for (int r = 0; r < 4; r++)
        hw[(qrow + r) * 200 + h * 32 + nt * 16 + l15] = f2bf(oall[h][nt][r]);

  // proj: xo = x + O @ w_proj + b_proj  (B-frags streamed from L2-resident wprojT)
  f32x4 accP[12];
  #pragma unroll
  for (int nt = 0; nt < 12; nt++) accP[nt] = (f32x4){0.f,0.f,0.f,0.f};
  #pragma unroll
  for (int k = 0; k < 6; k++){
    short8 af = *(const short8*)&hw[(w * 16 + l15) * 200 + k * 32 + quad * 8];
    #pragma unroll
    for (int nt = 0; nt < 12; nt++){
      short8 bfv = *(const short8*)(wprojT + (size_t)(nt * 16 + l15) * 192 + k * 32 + quad * 8);
      accP[nt] = __builtin_amdgcn_mfma_f32_16x16x32_bf16(af, bfv, accP[nt], 0, 0, 0);
    }
  }
  #pragma unroll
  for (int r = 0; r < 4; r++){
    int nn = qrow + r;
    int hr = hy * 8 + (nn >> 3), wcc = wx * 8 + (nn & 7);
    size_t tg = ((size_t)(b * 256 + hr)) * 256 + wcc;
    #pragma unroll
    for (int nt = 0; nt < 12; nt++){
      int col = nt * 16 + l15;
      size_t idx = tg * 192 + col;
      out[idx] = accP[nt][r] + bproj[col] + x[idx];
    }
  }
}

// ---------------- K2: fused LN2 + fc1 + GELU + fc2 + residual (in-place on io)
// v9: 32x32 fc2 + 16x16 fc1 (afr only 24 regs), global_load_lds staging
// (0 staging VGPRs — v8's spill fix), 77 KB LDS -> 2 blocks/CU (v7's occupancy
// fix): w1 double-buffered, w2 single; h2t aliases w2s; Ut aliases w1s[cur].
// Counted vmcnt: W1[ch+1]+W2[ch] in flight across each chunk's compute.
// Per-wave issue counts: W1 c1={7,6,6,6}, W2 c2={7,7,7,6}.
__global__ __launch_bounds__(256, 2) void mlp_fused(
    const float* __restrict__ g2, const float* __restrict__ b2,
    const u16* __restrict__ wfc1P, const float* __restrict__ bfc1,
    const u16* __restrict__ wfc2P, const float* __restrict__ bfc2,
    float* __restrict__ io)
{
  __shared__ u16 w1s[2][64 * 200];  // 2 x 25.6 KB fc1 chunk dbuf; Ut [64][72] aliases w1s[cur]
  __shared__ u16 w2s[192 * 72];     // 27.6 KB fc2 chunk; h2t [64][200] alias during LN
  u16* h2t = w2s;

  const int tid = threadIdx.x, lane = tid & 63, w = tid >> 6;
  const int l15 = lane & 15, quad = lane >> 4;
  const int l31 = lane & 31, half = lane >> 5;
  const int wm = w >> 1, wn = w & 1;
  const int t0 = blockIdx.x * 64;

  typedef const __attribute__((address_space(1))) void gv_t;
  typedef __attribute__((address_space(3))) void lv_t;

  // wave w stages items j = w, w+4, ... ; 1 KB per item (64 lanes x 16 B)
  #define ISSUE_W1(ch, buf)                                                        \
    { const u16* src = wfc1P + (size_t)(ch) * 12800;                               \
      _Pragma("unroll")                                                            \
      for (int t = 0; t < 7; ++t){ int j = w + t * 4;                              \
        if (j < 25)                                                                \
          __builtin_amdgcn_global_load_lds((gv_t*)(src + j * 512 + lane * 8),      \
                                           (lv_t*)&w1s[buf][j * 512], 16, 0, 0); } }
  #define ISSUE_W2(ch)                                                             \
    { const u16* src = wfc2P + (size_t)(ch) * 13824;                               \
      _Pragma("unroll")                                                            \
      for (int t = 0; t < 7; ++t){ int j = w + t * 4;                              \
        if (j < 27)                                                                \
          __builtin_amdgcn_global_load_lds((gv_t*)(src + j * 512 + lane * 8),      \
                                           (lv_t*)&w2s[j * 512], 16, 0, 0); } }

  // ---- LN2 into h2t (in w2s region) ----
  {
    int n = w * 16 + (lane >> 2), p = lane & 3;
    const float* xr = io + (size_t)(t0 + n) * 192 + p * 48;
    float v[48];
    #pragma unroll
    for (int c = 0; c < 12; c++) *(float4*)(v + c * 4) = *(const float4*)(xr + c * 4);
    float s = 0.f, ss = 0.f;
    #pragma unroll
    for (int i = 0; i < 48; i++){ s += v[i]; ss += v[i] * v[i]; }
    s += __shfl_xor(s, 1); ss += __shfl_xor(ss, 1);
    s += __shfl_xor(s, 2); ss += __shfl_xor(ss, 2);
    float m  = s * (1.f / 192.f);
    float rs = rsqrtf(ss * (1.f / 192.f) - m * m + 1e-5f);
    #pragma unroll
    for (int c = 0; c < 12; c++){
      float4 gv = *(const float4*)(g2 + p * 48 + c * 4);
      float4 bv = *(const float4*)(b2 + p * 48 + c * 4);
      short4v t;
      t.x = (short)f2bf((v[c*4+0] - m) * rs * gv.x + bv.x);
      t.y = (short)f2bf((v[c*4+1] - m) * rs * gv.y + bv.y);
      t.z = (short)f2bf((v[c*4+2] - m) * rs * gv.z + bv.z);
      t.w = (short)f2bf((v[c*4+3] - m) * rs * gv.w + bv.w);
      *(short4v*)&h2t[n * 200 + p * 48 + c * 4] = t;
    }
  }
  asm volatile("s_waitcnt lgkmcnt(0)\ns_barrier" ::: "memory");   // h2t visible

  // ---- fc1 A-fragments to regs: wave's 16 tokens, 6 k-steps (24 VGPR) ----
  short8 afr[6];
  #pragma unroll
  for (int k = 0; k < 6; ++k)
    afr[k] = *(const short8*)&h2t[(w * 16 + l15) * 200 + k * 32 + quad * 8];
  asm volatile("s_waitcnt lgkmcnt(0)\ns_barrier" ::: "memory");   // h2t dead; w2s free

  // prologue staging: W1[0], W2[0], W1[1] (order matters for vmcnt math)
  ISSUE_W1(0, 0);
  ISSUE_W2(0);
  ISSUE_W1(1, 1);

  f32x16 accO[3];
  #pragma unroll
  for (int t = 0; t < 3; ++t)
    #pragma unroll
    for (int i = 0; i < 16; ++i) accO[t][i] = 0.f;

  #pragma unroll
  for (int ch = 0; ch < 12; ++ch){
    const int cur = ch & 1;
    // wait W1[ch]: newer = W2[ch]+W1[ch+1] = 12..14 items -> vmcnt(12);
    // last chunk: newer = W2[11] only (6-7) -> vmcnt(6)
    if (ch < 11) asm volatile("s_waitcnt vmcnt(12) lgkmcnt(0)\ns_barrier" ::: "memory");
    else         asm volatile("s_waitcnt vmcnt(6) lgkmcnt(0)\ns_barrier" ::: "memory");

    // fc1: 16x16, wave = 16 tokens x 64 chunk-cols, K=192 (A from regs)
    f32x4 au[4];
    #pragma unroll
    for (int nt = 0; nt < 4; ++nt) au[nt] = (f32x4){0.f,0.f,0.f,0.f};
    #pragma unroll
    for (int k = 0; k < 6; ++k)
      #pragma unroll
      for (int nt = 0; nt < 4; ++nt){
        short8 bf = *(const short8*)&w1s[cur][(nt * 16 + l15) * 200 + k * 32 + quad * 8];
        au[nt] = __builtin_amdgcn_mfma_f32_16x16x32_bf16(afr[k], bf, au[nt], 0, 0, 0);
      }
    asm volatile("s_waitcnt lgkmcnt(0)\ns_barrier" ::: "memory");  // w1s[cur] reads done

    // bias + GELU -> Ut (aliases w1s[cur], [64][72])
    u16* Ut = &w1s[cur][0];
    #pragma unroll
    for (int nt = 0; nt < 4; ++nt){
      float bb = bfc1[ch * 64 + nt * 16 + l15];
      #pragma unroll
      for (int r = 0; r < 4; ++r)
        Ut[(w * 16 + quad * 4 + r) * 72 + nt * 16 + l15] = f2bf(gelu_fast(au[nt][r] + bb));
    }
    // Ut visible + W2[ch] arrived (newer = W1[ch+1] = 6-7 -> vmcnt(6); last: 0)
    if (ch < 11) asm volatile("s_waitcnt vmcnt(6) lgkmcnt(0)\ns_barrier" ::: "memory");
    else         asm volatile("s_waitcnt vmcnt(0) lgkmcnt(0)\ns_barrier" ::: "memory");

    // fc2: 32x32, wave tile 32 tok x 96 outcols, K=64
    #pragma unroll
    for (int ks = 0; ks < 4; ++ks){
      short8 uf = *(const short8*)&Ut[(wm * 32 + l31) * 72 + ks * 16 + half * 8];
      #pragma unroll
      for (int t = 0; t < 3; ++t){
        short8 bf = *(const short8*)&w2s[(wn * 96 + t * 32 + l31) * 72 + ks * 16 + half * 8];
        accO[t] = __builtin_amdgcn_mfma_f32_32x32x16_bf16(uf, bf, accO[t], 0, 0, 0);
      }
    }
    asm volatile("s_waitcnt lgkmcnt(0)\ns_barrier" ::: "memory");  // w2s & Ut reads done

    // stage ahead: W2[ch+1] into w2s (now free), W1[ch+2] into w1s[cur] (Ut dead)
    if (ch < 11) ISSUE_W2(ch + 1);
    if (ch < 10) ISSUE_W1(ch + 2, cur);
  }

  // epilogue: out = xo + (accO + b_fc2), in place (block-disjoint rows)
  #pragma unroll
  for (int t = 0; t < 3; ++t){
    int col = wn * 96 + t * 32 + l31;
    float bbo = bfc2[col];
    #pragma unroll
    for (int r = 0; r < 16; ++r){
      int row = t0 + wm * 32 + (r & 3) + 8 * (r >> 2) + 4 * half;
      size_t idx = (size_t)row * 192 + col;
      io[idx] = accO[t][r] + bbo + io[idx];
    }
  }
  #undef ISSUE_W1
  #undef ISSUE_W2
}

// ------------------------------------------------------------------------
extern "C" void kernel_launch(void* const* d_in, const int* in_sizes, int n_in,
                              void* d_out, int out_size, void* d_ws, size_t ws_size,
                              hipStream_t stream) {
  const float* x      = (const float*)d_in[0];
  const float* g1     = (const float*)d_in[1];
  const float* b1     = (const float*)d_in[2];
  const float* w_qkv  = (const float*)d_in[3];
  const float* b_qkv  = (const float*)d_in[4];
  const float* w_proj = (const float*)d_in[5];
  const float* b_proj = (const float*)d_in[6];
  const float* g2     = (const float*)d_in[7];
  const float* b2     = (const float*)d_in[8];
  const float* w_fc1  = (const float*)d_in[9];
  const float* b_fc1  = (const float*)d_in[10];
  const float* w_fc2  = (const float*)d_in[11];
  const float* b_fc2  = (const float*)d_in[12];
  float* out = (float*)d_out;

  // workspace: transposed bf16 weights (<1 MB)
  u16* wqkvT  = (u16*)d_ws;                      // 576x192
  u16* wprojT = wqkvT  + 576 * 192;              // 192x192
  u16* wfc1P  = wprojT + 192 * 192;              // 12 x (64x200)  chunk-contiguous
  u16* wfc2P  = wfc1P  + 12 * 12800;             // 12 x (192x72)  chunk-contiguous

  transpose_all<<<dim3(576, 4), 256, 0, stream>>>(w_qkv, wqkvT, w_proj, wprojT,
                                                  w_fc1, wfc1P, w_fc2, wfc2P);
  // d_out = x + attn(LN1(x)) @ w_proj + b_proj   (window-fused)
  win_attn<<<4096, 256, 0, stream>>>(x, g1, b1, wqkvT, b_qkv, wprojT, b_proj, out);
  // d_out += gelu(LN2(d_out) @ w_fc1 + b_fc1) @ w_fc2 + b_fc2   (in place)
  mlp_fused<<<4096, 256, 0, stream>>>(g2, b2, wfc1P, b_fc1, wfc2P, b_fc2, out);
}

// Round 10
// 888.360 us; speedup vs baseline: 1.6412x; 1.0192x over previous
//
#include <hip/hip_runtime.h>
#include <hip/hip_bf16.h>

typedef unsigned short u16;
typedef __attribute__((ext_vector_type(8))) short short8;
typedef __attribute__((ext_vector_type(4))) short short4v;
typedef __attribute__((ext_vector_type(4))) float f32x4;
typedef __attribute__((ext_vector_type(16))) float f32x16;

__device__ __forceinline__ u16 f2bf(float f){
  __hip_bfloat16 h = __float2bfloat16(f);
  return *reinterpret_cast<u16*>(&h);
}

// fast GELU: tanh form computed as u * sigmoid(2y). Validated r1-r9:
// absmax unchanged (0.03125), bf16 rounding dominates.
__device__ __forceinline__ float gelu_fast(float u){
  float uu = u * u;
  float e = __expf(u * fmaf(uu, -0.0713548163f, -1.5957691216f));
  return u * __builtin_amdgcn_rcpf(1.f + e);
}

// ---------------- weight transpose+convert ----------------
// d0: wqkvP  [6 heads][96][200]+pad  chunk-contiguous, 38912 B = 38 x 1KB items
// d1: wprojT [192][192]              (win_attn proj, L2-streamed)
// d2: wfc1P  [12 chunks][64][200]    25600 B = 25 x 1KB  (v7/v9-proven)
// d3: wfc2P  [12 chunks][192][72]    27648 B = 27 x 1KB  (v7/v9-proven)
__global__ void transpose_all(const float* __restrict__ w0, u16* __restrict__ d0,   // 192x576
                              const float* __restrict__ w1, u16* __restrict__ d1,   // 192x192
                              const float* __restrict__ w2, u16* __restrict__ d2,   // 192x768
                              const float* __restrict__ w3, u16* __restrict__ d3)   // 768x192
{
  int seg = blockIdx.y;
  int idx = blockIdx.x * 256 + threadIdx.x;
  if (seg == 0){
    // w_qkv [192][576]: k=idx/576, n=idx%576. n = mat*192 + head*32 + r32
    if (idx < 192 * 576){
      int k = idx / 576, n = idx % 576;
      int mat = n / 192, r = n % 192;
      int head = r >> 5, r32 = r & 31;
      d0[(size_t)head * 19456 + (mat * 32 + r32) * 200 + k] = f2bf(w0[idx]);
    }
  } else if (seg == 1){
    if (idx < 192 * 192){ int k = idx / 192, n = idx % 192; d1[n * 192 + k] = f2bf(w1[idx]); }
  } else if (seg == 2){
    if (idx < 192 * 768){
      int k = idx / 768, n = idx % 768;
      d2[(size_t)(n >> 6) * 12800 + (n & 63) * 200 + k] = f2bf(w2[idx]);
    }
  } else {
    if (idx < 768 * 192){
      int k = idx / 192, n = idx % 192;
      d3[(size_t)(k >> 6) * 13824 + n * 72 + (k & 63)] = f2bf(w3[idx]);
    }
  }
}

// ---------------- K1: fused LN1 + QKV + window attention + proj + residual
// v10 (v9 recipe ported): QKV A-frags hoisted to regs (24 VGPR) -> hw dies ->
// attn buffers ALIAS hw; weight chunk gll-staged (0 VGPRs) into 38 KB wch,
// head h+1 staged during head h's attention phase (counted vmcnt, raw
// s_barrier, no vmcnt(0) drain mid-pipeline). LDS 63.6 KB -> 2 blocks/CU.
// 3 barriers/head (was 4).
__global__ __launch_bounds__(256, 2) void win_attn(
    const float* __restrict__ x,  const float* __restrict__ g1, const float* __restrict__ b1,
    const u16* __restrict__ wqkvP, const float* __restrict__ bqkv,
    const u16* __restrict__ wprojT, const float* __restrict__ bproj,
    float* __restrict__ out)
{
  __shared__ u16 hw[64 * 200];     // LN1 tokens; after afr-hoist aliased:
  __shared__ u16 wch[19456];       // 38 KB gll-staged weight chunk [96][200]+pad
  u16* Ql = hw;                    // 64 x 40
  u16* Kl = hw + 2560;             // 64 x 40
  u16* Vt = hw + 5120;             // 32 x 72 (V transposed: [ch][token])
  u16* Pl = hw + 7424;             // 64 x 72 (P, rows wave-private)  end=12032<12800

  const int tid = threadIdx.x, lane = tid & 63, w = tid >> 6;
  const int l15 = lane & 15, quad = lane >> 4;
  const int wid = blockIdx.x;
  const int b = wid >> 10, hy = (wid >> 5) & 31, wx = wid & 31;

  typedef const __attribute__((address_space(1))) void gv_t;
  typedef __attribute__((address_space(3))) void lv_t;

  // wave w stages items j = w, w+4, ...  (1 KB per item: 64 lanes x 16 B)
  #define ISSUE_QKV(h)                                                           \
    { const u16* src = wqkvP + (size_t)(h) * 19456;                              \
      _Pragma("unroll")                                                          \
      for (int t = 0; t < 10; ++t){ int j = w + t * 4;                           \
        if (j < 38)                                                              \
          __builtin_amdgcn_global_load_lds((gv_t*)(src + j * 512 + lane * 8),    \
                                           (lv_t*)&wch[j * 512], 16, 0, 0); } }

  ISSUE_QKV(0);   // head-0 chunk flies under LN

  // ---- LN1 into hw: 4 lanes per token, 16 tokens per wave ----
  {
    int n = w * 16 + (lane >> 2), p = lane & 3;
    int hr = hy * 8 + (n >> 3), wcc = wx * 8 + (n & 7);
    size_t tg = ((size_t)(b * 256 + hr)) * 256 + wcc;
    const float* xr = x + tg * 192 + p * 48;
    float v[48];
    #pragma unroll
    for (int c = 0; c < 12; c++) *(float4*)(v + c * 4) = *(const float4*)(xr + c * 4);
    float s = 0.f, ss = 0.f;
    #pragma unroll
    for (int i = 0; i < 48; i++){ s += v[i]; ss += v[i] * v[i]; }
    s += __shfl_xor(s, 1); ss += __shfl_xor(ss, 1);
    s += __shfl_xor(s, 2); ss += __shfl_xor(ss, 2);
    float m  = s * (1.f / 192.f);
    float rs = rsqrtf(ss * (1.f / 192.f) - m * m + 1e-5f);
    #pragma unroll
    for (int c = 0; c < 12; c++){
      float4 gv = *(const float4*)(g1 + p * 48 + c * 4);
      float4 bv = *(const float4*)(b1 + p * 48 + c * 4);
      short4v t;
      t.x = (short)f2bf((v[c*4+0] - m) * rs * gv.x + bv.x);
      t.y = (short)f2bf((v[c*4+1] - m) * rs * gv.y + bv.y);
      t.z = (short)f2bf((v[c*4+2] - m) * rs * gv.z + bv.z);
      t.w = (short)f2bf((v[c*4+3] - m) * rs * gv.w + bv.w);
      *(short4v*)&hw[n * 200 + p * 48 + c * 4] = t;
    }
  }
  asm volatile("s_waitcnt lgkmcnt(0)\ns_barrier" ::: "memory");   // hw visible

  // ---- QKV A-fragments to regs: wave's 16 tokens, 6 k-steps (24 VGPR) ----
  short8 afr[6];
  #pragma unroll
  for (int k = 0; k < 6; ++k)
    afr[k] = *(const short8*)&hw[(w * 16 + l15) * 200 + k * 32 + quad * 8];
  // hw now dead (per-wave reads complete before own step-1 wait below;
  // first write into the aliased region is 2 barriers later)

  const int qrow = w * 16 + quad * 4;   // +r gives this lane's C-layout rows
  f32x4 oall[6][2];
  #pragma unroll
  for (int h = 0; h < 6; h++)
    #pragma unroll
    for (int nt = 0; nt < 2; nt++) oall[h][nt] = (f32x4){0.f, 0.f, 0.f, 0.f};

  #pragma unroll
  for (int head = 0; head < 6; ++head){
    // step 1: staged chunk landed (issued a full attn-phase ago) + all waves sync
    asm volatile("s_waitcnt vmcnt(0) lgkmcnt(0)\ns_barrier" ::: "memory");

    // step 2: QKV MFMA — A from regs, B from wch
    f32x4 acc[3][2];
    #pragma unroll
    for (int mat = 0; mat < 3; mat++)
      #pragma unroll
      for (int nt = 0; nt < 2; nt++) acc[mat][nt] = (f32x4){0.f, 0.f, 0.f, 0.f};
    #pragma unroll
    for (int k = 0; k < 6; k++)
      #pragma unroll
      for (int mat = 0; mat < 3; mat++)
        #pragma unroll
        for (int nt = 0; nt < 2; nt++){
          short8 bfv = *(const short8*)&wch[(mat * 32 + nt * 16 + l15) * 200 + k * 32 + quad * 8];
          acc[mat][nt] = __builtin_amdgcn_mfma_f32_16x16x32_bf16(afr[k], bfv, acc[mat][nt], 0, 0, 0);
        }
    // step 3: all waves' wch reads done -> wch free for next head's gll
    asm volatile("s_waitcnt lgkmcnt(0)\ns_barrier" ::: "memory");

    // step 4: prefetch next head's chunk (flies across attn phase); QKV->LDS
    if (head < 5) ISSUE_QKV(head + 1);
    #pragma unroll
    for (int nt = 0; nt < 2; nt++){
      float bq = bqkv[      head * 32 + nt * 16 + l15];
      float bk = bqkv[192 + head * 32 + nt * 16 + l15];
      float bv = bqkv[384 + head * 32 + nt * 16 + l15];
      #pragma unroll
      for (int r = 0; r < 4; r++){
        Ql[(qrow + r) * 40 + nt * 16 + l15] = f2bf(acc[0][nt][r] + bq);
        Kl[(qrow + r) * 40 + nt * 16 + l15] = f2bf(acc[1][nt][r] + bk);
        Vt[(nt * 16 + l15) * 72 + qrow + r] = f2bf(acc[2][nt][r] + bv);
      }
    }
    // step 5: K/V visible cross-wave
    asm volatile("s_waitcnt lgkmcnt(0)\ns_barrier" ::: "memory");

    // step 6: S = Q K^T (hd=32 == one k-step)
    short8 aq = *(const short8*)&Ql[(w * 16 + l15) * 40 + quad * 8];
    f32x4 sa[4];
    #pragma unroll
    for (int kt = 0; kt < 4; kt++){
      short8 bk8 = *(const short8*)&Kl[(kt * 16 + l15) * 40 + quad * 8];
      sa[kt] = __builtin_amdgcn_mfma_f32_16x16x32_bf16(aq, bk8, (f32x4){0.f,0.f,0.f,0.f}, 0, 0, 0);
    }
    const float scale = 0.17677669529663687f;  // 32^-0.5
    float inv[4];
    #pragma unroll
    for (int r = 0; r < 4; r++){
      float s0 = sa[0][r] * scale, s1 = sa[1][r] * scale;
      float s2 = sa[2][r] * scale, s3 = sa[3][r] * scale;
      float mx = fmaxf(fmaxf(s0, s1), fmaxf(s2, s3));
      mx = fmaxf(mx, __shfl_xor(mx, 1)); mx = fmaxf(mx, __shfl_xor(mx, 2));
      mx = fmaxf(mx, __shfl_xor(mx, 4)); mx = fmaxf(mx, __shfl_xor(mx, 8));
      float p0 = __expf(s0 - mx), p1 = __expf(s1 - mx);
      float p2 = __expf(s2 - mx), p3 = __expf(s3 - mx);
      float l = p0 + p1 + p2 + p3;
      l += __shfl_xor(l, 1); l += __shfl_xor(l, 2);
      l += __shfl_xor(l, 4); l += __shfl_xor(l, 8);
      inv[r] = 1.f / l;
      Pl[(qrow + r) * 72 +      l15] = f2bf(p0);
      Pl[(qrow + r) * 72 + 16 + l15] = f2bf(p1);
      Pl[(qrow + r) * 72 + 32 + l15] = f2bf(p2);
      Pl[(qrow + r) * 72 + 48 + l15] = f2bf(p3);
    }
    // O = P V  (Pl rows wave-private; Vt barrier already passed)
    f32x4 oa[2];
    oa[0] = (f32x4){0.f,0.f,0.f,0.f}; oa[1] = (f32x4){0.f,0.f,0.f,0.f};
    #pragma unroll
    for (int ks = 0; ks < 2; ks++){
      short8 ap = *(const short8*)&Pl[(w * 16 + l15) * 72 + ks * 32 + quad * 8];
      #pragma unroll
      for (int nt = 0; nt < 2; nt++){
        short8 bv8 = *(const short8*)&Vt[(nt * 16 + l15) * 72 + ks * 32 + quad * 8];
        oa[nt] = __builtin_amdgcn_mfma_f32_16x16x32_bf16(ap, bv8, oa[nt], 0, 0, 0);
      }
    }
    #pragma unroll
    for (int nt = 0; nt < 2; nt++)
      #pragma unroll
      for (int r = 0; r < 4; r++)
        oall[head][nt][r] = oa[nt][r] * inv[r];
  }

  // all attn-buffer readers done before O stash overwrites the region
  asm volatile("s_waitcnt lgkmcnt(0)\ns_barrier" ::: "memory");

  // stash O (64x192, bf16) into hw (rows wave-private)
  #pragma unroll
  for (int h = 0; h < 6; h++)
    #pragma unroll
    for (int nt = 0; nt < 2; nt++)
      #pragma unroll
      for (int r = 0; r < 4; r++)
        hw[(qrow + r) * 200 + h * 32 + nt * 16 + l15] = f2bf(oall[h][nt][r]);

  // proj: xo = x + O @ w_proj + b_proj  (B-frags streamed from L2-resident wprojT)
  f32x4 accP[12];
  #pragma unroll
  for (int nt = 0; nt < 12; nt++) accP[nt] = (f32x4){0.f,0.f,0.f,0.f};
  #pragma unroll
  for (int k = 0; k < 6; k++){
    short8 af = *(const short8*)&hw[(w * 16 + l15) * 200 + k * 32 + quad * 8];
    #pragma unroll
    for (int nt = 0; nt < 12; nt++){
      short8 bfv = *(const short8*)(wprojT + (size_t)(nt * 16 + l15) * 192 + k * 32 + quad * 8);
      accP[nt] = __builtin_amdgcn_mfma_f32_16x16x32_bf16(af, bfv, accP[nt], 0, 0, 0);
    }
  }
  #pragma unroll
  for (int r = 0; r < 4; r++){
    int nn = qrow + r;
    int hr = hy * 8 + (nn >> 3), wcc = wx * 8 + (nn & 7);
    size_t tg = ((size_t)(b * 256 + hr)) * 256 + wcc;
    #pragma unroll
    for (int nt = 0; nt < 12; nt++){
      int col = nt * 16 + l15;
      size_t idx = tg * 192 + col;
      out[idx] = accP[nt][r] + bproj[col] + x[idx];
    }
  }
  #undef ISSUE_QKV
}

// ---------------- K2: fused LN2 + fc1 + GELU + fc2 + residual (in-place on io)
// v9 kept byte-exact (est ~346us): 16x16 fc1 (afr 24 regs) + 32x32 fc2,
// global_load_lds staging, counted vmcnt, 77 KB LDS -> 2 blocks/CU.
__global__ __launch_bounds__(256, 2) void mlp_fused(
    const float* __restrict__ g2, const float* __restrict__ b2,
    const u16* __restrict__ wfc1P, const float* __restrict__ bfc1,
    const u16* __restrict__ wfc2P, const float* __restrict__ bfc2,
    float* __restrict__ io)
{
  __shared__ u16 w1s[2][64 * 200];  // 2 x 25.6 KB fc1 chunk dbuf; Ut [64][72] aliases w1s[cur]
  __shared__ u16 w2s[192 * 72];     // 27.6 KB fc2 chunk; h2t [64][200] alias during LN
  u16* h2t = w2s;

  const int tid = threadIdx.x, lane = tid & 63, w = tid >> 6;
  const int l15 = lane & 15, quad = lane >> 4;
  const int l31 = lane & 31, half = lane >> 5;
  const int wm = w >> 1, wn = w & 1;
  const int t0 = blockIdx.x * 64;

  typedef const __attribute__((address_space(1))) void gv_t;
  typedef __attribute__((address_space(3))) void lv_t;

  #define ISSUE_W1(ch, buf)                                                        \
    { const u16* src = wfc1P + (size_t)(ch) * 12800;                               \
      _Pragma("unroll")                                                            \
      for (int t = 0; t < 7; ++t){ int j = w + t * 4;                              \
        if (j < 25)                                                                \
          __builtin_amdgcn_global_load_lds((gv_t*)(src + j * 512 + lane * 8),      \
                                           (lv_t*)&w1s[buf][j * 512], 16, 0, 0); } }
  #define ISSUE_W2(ch)                                                             \
    { const u16* src = wfc2P + (size_t)(ch) * 13824;                               \
      _Pragma("unroll")                                                            \
      for (int t = 0; t < 7; ++t){ int j = w + t * 4;                              \
        if (j < 27)                                                                \
          __builtin_amdgcn_global_load_lds((gv_t*)(src + j * 512 + lane * 8),      \
                                           (lv_t*)&w2s[j * 512], 16, 0, 0); } }

  // ---- LN2 into h2t (in w2s region) ----
  {
    int n = w * 16 + (lane >> 2), p = lane & 3;
    const float* xr = io + (size_t)(t0 + n) * 192 + p * 48;
    float v[48];
    #pragma unroll
    for (int c = 0; c < 12; c++) *(float4*)(v + c * 4) = *(const float4*)(xr + c * 4);
    float s = 0.f, ss = 0.f;
    #pragma unroll
    for (int i = 0; i < 48; i++){ s += v[i]; ss += v[i] * v[i]; }
    s += __shfl_xor(s, 1); ss += __shfl_xor(ss, 1);
    s += __shfl_xor(s, 2); ss += __shfl_xor(ss, 2);
    float m  = s * (1.f / 192.f);
    float rs = rsqrtf(ss * (1.f / 192.f) - m * m + 1e-5f);
    #pragma unroll
    for (int c = 0; c < 12; c++){
      float4 gv = *(const float4*)(g2 + p * 48 + c * 4);
      float4 bv = *(const float4*)(b2 + p * 48 + c * 4);
      short4v t;
      t.x = (short)f2bf((v[c*4+0] - m) * rs * gv.x + bv.x);
      t.y = (short)f2bf((v[c*4+1] - m) * rs * gv.y + bv.y);
      t.z = (short)f2bf((v[c*4+2] - m) * rs * gv.z + bv.z);
      t.w = (short)f2bf((v[c*4+3] - m) * rs * gv.w + bv.w);
      *(short4v*)&h2t[n * 200 + p * 48 + c * 4] = t;
    }
  }
  asm volatile("s_waitcnt lgkmcnt(0)\ns_barrier" ::: "memory");   // h2t visible

  // ---- fc1 A-fragments to regs: wave's 16 tokens, 6 k-steps (24 VGPR) ----
  short8 afr[6];
  #pragma unroll
  for (int k = 0; k < 6; ++k)
    afr[k] = *(const short8*)&h2t[(w * 16 + l15) * 200 + k * 32 + quad * 8];
  asm volatile("s_waitcnt lgkmcnt(0)\ns_barrier" ::: "memory");   // h2t dead; w2s free

  // prologue staging: W1[0], W2[0], W1[1] (order matters for vmcnt math)
  ISSUE_W1(0, 0);
  ISSUE_W2(0);
  ISSUE_W1(1, 1);

  f32x16 accO[3];
  #pragma unroll
  for (int t = 0; t < 3; ++t)
    #pragma unroll
    for (int i = 0; i < 16; ++i) accO[t][i] = 0.f;

  #pragma unroll
  for (int ch = 0; ch < 12; ++ch){
    const int cur = ch & 1;
    // wait W1[ch]: newer = W2[ch]+W1[ch+1] -> vmcnt(12); last chunk: W2[11] -> vmcnt(6)
    if (ch < 11) asm volatile("s_waitcnt vmcnt(12) lgkmcnt(0)\ns_barrier" ::: "memory");
    else         asm volatile("s_waitcnt vmcnt(6) lgkmcnt(0)\ns_barrier" ::: "memory");

    // fc1: 16x16, wave = 16 tokens x 64 chunk-cols, K=192 (A from regs)
    f32x4 au[4];
    #pragma unroll
    for (int nt = 0; nt < 4; ++nt) au[nt] = (f32x4){0.f,0.f,0.f,0.f};
    #pragma unroll
    for (int k = 0; k < 6; ++k)
      #pragma unroll
      for (int nt = 0; nt < 4; ++nt){
        short8 bf = *(const short8*)&w1s[cur][(nt * 16 + l15) * 200 + k * 32 + quad * 8];
        au[nt] = __builtin_amdgcn_mfma_f32_16x16x32_bf16(afr[k], bf, au[nt], 0, 0, 0);
      }
    asm volatile("s_waitcnt lgkmcnt(0)\ns_barrier" ::: "memory");  // w1s[cur] reads done

    // bias + GELU -> Ut (aliases w1s[cur], [64][72])
    u16* Ut = &w1s[cur][0];
    #pragma unroll
    for (int nt = 0; nt < 4; ++nt){
      float bb = bfc1[ch * 64 + nt * 16 + l15];
      #pragma unroll
      for (int r = 0; r < 4; ++r)
        Ut[(w * 16 + quad * 4 + r) * 72 + nt * 16 + l15] = f2bf(gelu_fast(au[nt][r] + bb));
    }
    // Ut visible + W2[ch] arrived (newer = W1[ch+1] -> vmcnt(6); last: 0)
    if (ch < 11) asm volatile("s_waitcnt vmcnt(6) lgkmcnt(0)\ns_barrier" ::: "memory");
    else         asm volatile("s_waitcnt vmcnt(0) lgkmcnt(0)\ns_barrier" ::: "memory");

    // fc2: 32x32, wave tile 32 tok x 96 outcols, K=64
    #pragma unroll
    for (int ks = 0; ks < 4; ++ks){
      short8 uf = *(const short8*)&Ut[(wm * 32 + l31) * 72 + ks * 16 + half * 8];
      #pragma unroll
      for (int t = 0; t < 3; ++t){
        short8 bf = *(const short8*)&w2s[(wn * 96 + t * 32 + l31) * 72 + ks * 16 + half * 8];
        accO[t] = __builtin_amdgcn_mfma_f32_32x32x16_bf16(uf, bf, accO[t], 0, 0, 0);
      }
    }
    asm volatile("s_waitcnt lgkmcnt(0)\ns_barrier" ::: "memory");  // w2s & Ut reads done

    // stage ahead: W2[ch+1] into w2s (now free), W1[ch+2] into w1s[cur] (Ut dead)
    if (ch < 11) ISSUE_W2(ch + 1);
    if (ch < 10) ISSUE_W1(ch + 2, cur);
  }

  // epilogue: out = xo + (accO + b_fc2), in place (block-disjoint rows)
  #pragma unroll
  for (int t = 0; t < 3; ++t){
    int col = wn * 96 + t * 32 + l31;
    float bbo = bfc2[col];
    #pragma unroll
    for (int r = 0; r < 16; ++r){
      int row = t0 + wm * 32 + (r & 3) + 8 * (r >> 2) + 4 * half;
      size_t idx = (size_t)row * 192 + col;
      io[idx] = accO[t][r] + bbo + io[idx];
    }
  }
  #undef ISSUE_W1
  #undef ISSUE_W2
}

// ------------------------------------------------------------------------
extern "C" void kernel_launch(void* const* d_in, const int* in_sizes, int n_in,
                              void* d_out, int out_size, void* d_ws, size_t ws_size,
                              hipStream_t stream) {
  const float* x      = (const float*)d_in[0];
  const float* g1     = (const float*)d_in[1];
  const float* b1     = (const float*)d_in[2];
  const float* w_qkv  = (const float*)d_in[3];
  const float* b_qkv  = (const float*)d_in[4];
  const float* w_proj = (const float*)d_in[5];
  const float* b_proj = (const float*)d_in[6];
  const float* g2     = (const float*)d_in[7];
  const float* b2     = (const float*)d_in[8];
  const float* w_fc1  = (const float*)d_in[9];
  const float* b_fc1  = (const float*)d_in[10];
  const float* w_fc2  = (const float*)d_in[11];
  const float* b_fc2  = (const float*)d_in[12];
  float* out = (float*)d_out;

  // workspace: transposed bf16 weights (<1 MB)
  u16* wqkvP  = (u16*)d_ws;                      // 6 x (96x200+pad) = 116736 u16
  u16* wprojT = wqkvP  + 6 * 19456;              // 192x192
  u16* wfc1P  = wprojT + 192 * 192;              // 12 x (64x200)  chunk-contiguous
  u16* wfc2P  = wfc1P  + 12 * 12800;             // 12 x (192x72)  chunk-contiguous

  transpose_all<<<dim3(576, 4), 256, 0, stream>>>(w_qkv, wqkvP, w_proj, wprojT,
                                                  w_fc1, wfc1P, w_fc2, wfc2P);
  // d_out = x + attn(LN1(x)) @ w_proj + b_proj   (window-fused)
  win_attn<<<4096, 256, 0, stream>>>(x, g1, b1, wqkvP, b_qkv, wprojT, b_proj, out);
  // d_out += gelu(LN2(d_out) @ w_fc1 + b_fc1) @ w_fc2 + b_fc2   (in place)
  mlp_fused<<<4096, 256, 0, stream>>>(g2, b2, wfc1P, b_fc1, wfc2P, b_fc2, out);
}

// Round 11
// 836.493 us; speedup vs baseline: 1.7430x; 1.0620x over previous
//
#include <hip/hip_runtime.h>
#include <hip/hip_bf16.h>

typedef unsigned short u16;
typedef __attribute__((ext_vector_type(8))) short short8;
typedef __attribute__((ext_vector_type(4))) short short4v;
typedef __attribute__((ext_vector_type(4))) float f32x4;
typedef __attribute__((ext_vector_type(16))) float f32x16;

__device__ __forceinline__ u16 f2bf(float f){
  __hip_bfloat16 h = __float2bfloat16(f);
  return *reinterpret_cast<u16*>(&h);
}

// fast GELU: tanh form computed as u * sigmoid(2y). Validated r1-r10:
// absmax unchanged (0.03125), bf16 rounding dominates.
__device__ __forceinline__ float gelu_fast(float u){
  float uu = u * u;
  float e = __expf(u * fmaf(uu, -0.0713548163f, -1.5957691216f));
  return u * __builtin_amdgcn_rcpf(1.f + e);
}

// ---------------- weight transpose+convert ----------------
// d0: wqkvP  [6 heads][96][200]+pad  chunk-contiguous, 38912 B = 38 x 1KB items
// d1: wprojT [192][192]              (win_attn proj, L2-streamed)
// d2: wfc1P  [12 chunks][64][200]    25600 B = 25 x 1KB  (v7/v9-proven)
// d3: wfc2P  [12 chunks][192][72]    27648 B = 27 x 1KB  (v7/v9-proven)
__global__ void transpose_all(const float* __restrict__ w0, u16* __restrict__ d0,   // 192x576
                              const float* __restrict__ w1, u16* __restrict__ d1,   // 192x192
                              const float* __restrict__ w2, u16* __restrict__ d2,   // 192x768
                              const float* __restrict__ w3, u16* __restrict__ d3)   // 768x192
{
  int seg = blockIdx.y;
  int idx = blockIdx.x * 256 + threadIdx.x;
  if (seg == 0){
    // w_qkv [192][576]: k=idx/576, n=idx%576. n = mat*192 + head*32 + r32
    if (idx < 192 * 576){
      int k = idx / 576, n = idx % 576;
      int mat = n / 192, r = n % 192;
      int head = r >> 5, r32 = r & 31;
      d0[(size_t)head * 19456 + (mat * 32 + r32) * 200 + k] = f2bf(w0[idx]);
    }
  } else if (seg == 1){
    if (idx < 192 * 192){ int k = idx / 192, n = idx % 192; d1[n * 192 + k] = f2bf(w1[idx]); }
  } else if (seg == 2){
    if (idx < 192 * 768){
      int k = idx / 768, n = idx % 768;
      d2[(size_t)(n >> 6) * 12800 + (n & 63) * 200 + k] = f2bf(w2[idx]);
    }
  } else {
    if (idx < 768 * 192){
      int k = idx / 192, n = idx % 192;
      d3[(size_t)(k >> 6) * 13824 + n * 72 + (k & 63)] = f2bf(w3[idx]);
    }
  }
}

// ---------------- K1: fused LN1 + QKV + window attention + proj + residual
// v10 kept byte-exact (measured 363us): QKV A-frags in regs, attn buffers
// alias hw, gll-staged weight chunk, counted vmcnt, 2 blocks/CU.
__global__ __launch_bounds__(256, 2) void win_attn(
    const float* __restrict__ x,  const float* __restrict__ g1, const float* __restrict__ b1,
    const u16* __restrict__ wqkvP, const float* __restrict__ bqkv,
    const u16* __restrict__ wprojT, const float* __restrict__ bproj,
    float* __restrict__ out)
{
  __shared__ u16 hw[64 * 200];     // LN1 tokens; after afr-hoist aliased:
  __shared__ u16 wch[19456];       // 38 KB gll-staged weight chunk [96][200]+pad
  u16* Ql = hw;                    // 64 x 40
  u16* Kl = hw + 2560;             // 64 x 40
  u16* Vt = hw + 5120;             // 32 x 72 (V transposed: [ch][token])
  u16* Pl = hw + 7424;             // 64 x 72 (P, rows wave-private)  end=12032<12800

  const int tid = threadIdx.x, lane = tid & 63, w = tid >> 6;
  const int l15 = lane & 15, quad = lane >> 4;
  const int wid = blockIdx.x;
  const int b = wid >> 10, hy = (wid >> 5) & 31, wx = wid & 31;

  typedef const __attribute__((address_space(1))) void gv_t;
  typedef __attribute__((address_space(3))) void lv_t;

  // wave w stages items j = w, w+4, ...  (1 KB per item: 64 lanes x 16 B)
  #define ISSUE_QKV(h)                                                           \
    { const u16* src = wqkvP + (size_t)(h) * 19456;                              \
      _Pragma("unroll")                                                          \
      for (int t = 0; t < 10; ++t){ int j = w + t * 4;                           \
        if (j < 38)                                                              \
          __builtin_amdgcn_global_load_lds((gv_t*)(src + j * 512 + lane * 8),    \
                                           (lv_t*)&wch[j * 512], 16, 0, 0); } }

  ISSUE_QKV(0);   // head-0 chunk flies under LN

  // ---- LN1 into hw: 4 lanes per token, 16 tokens per wave ----
  {
    int n = w * 16 + (lane >> 2), p = lane & 3;
    int hr = hy * 8 + (n >> 3), wcc = wx * 8 + (n & 7);
    size_t tg = ((size_t)(b * 256 + hr)) * 256 + wcc;
    const float* xr = x + tg * 192 + p * 48;
    float v[48];
    #pragma unroll
    for (int c = 0; c < 12; c++) *(float4*)(v + c * 4) = *(const float4*)(xr + c * 4);
    float s = 0.f, ss = 0.f;
    #pragma unroll
    for (int i = 0; i < 48; i++){ s += v[i]; ss += v[i] * v[i]; }
    s += __shfl_xor(s, 1); ss += __shfl_xor(ss, 1);
    s += __shfl_xor(s, 2); ss += __shfl_xor(ss, 2);
    float m  = s * (1.f / 192.f);
    float rs = rsqrtf(ss * (1.f / 192.f) - m * m + 1e-5f);
    #pragma unroll
    for (int c = 0; c < 12; c++){
      float4 gv = *(const float4*)(g1 + p * 48 + c * 4);
      float4 bv = *(const float4*)(b1 + p * 48 + c * 4);
      short4v t;
      t.x = (short)f2bf((v[c*4+0] - m) * rs * gv.x + bv.x);
      t.y = (short)f2bf((v[c*4+1] - m) * rs * gv.y + bv.y);
      t.z = (short)f2bf((v[c*4+2] - m) * rs * gv.z + bv.z);
      t.w = (short)f2bf((v[c*4+3] - m) * rs * gv.w + bv.w);
      *(short4v*)&hw[n * 200 + p * 48 + c * 4] = t;
    }
  }
  asm volatile("s_waitcnt lgkmcnt(0)\ns_barrier" ::: "memory");   // hw visible

  // ---- QKV A-fragments to regs: wave's 16 tokens, 6 k-steps (24 VGPR) ----
  short8 afr[6];
  #pragma unroll
  for (int k = 0; k < 6; ++k)
    afr[k] = *(const short8*)&hw[(w * 16 + l15) * 200 + k * 32 + quad * 8];

  const int qrow = w * 16 + quad * 4;   // +r gives this lane's C-layout rows
  f32x4 oall[6][2];
  #pragma unroll
  for (int h = 0; h < 6; h++)
    #pragma unroll
    for (int nt = 0; nt < 2; nt++) oall[h][nt] = (f32x4){0.f, 0.f, 0.f, 0.f};

  #pragma unroll
  for (int head = 0; head < 6; ++head){
    // step 1: staged chunk landed (issued a full attn-phase ago) + all waves sync
    asm volatile("s_waitcnt vmcnt(0) lgkmcnt(0)\ns_barrier" ::: "memory");

    // step 2: QKV MFMA — A from regs, B from wch
    f32x4 acc[3][2];
    #pragma unroll
    for (int mat = 0; mat < 3; mat++)
      #pragma unroll
      for (int nt = 0; nt < 2; nt++) acc[mat][nt] = (f32x4){0.f, 0.f, 0.f, 0.f};
    #pragma unroll
    for (int k = 0; k < 6; k++)
      #pragma unroll
      for (int mat = 0; mat < 3; mat++)
        #pragma unroll
        for (int nt = 0; nt < 2; nt++){
          short8 bfv = *(const short8*)&wch[(mat * 32 + nt * 16 + l15) * 200 + k * 32 + quad * 8];
          acc[mat][nt] = __builtin_amdgcn_mfma_f32_16x16x32_bf16(afr[k], bfv, acc[mat][nt], 0, 0, 0);
        }
    // step 3: all waves' wch reads done -> wch free for next head's gll
    asm volatile("s_waitcnt lgkmcnt(0)\ns_barrier" ::: "memory");

    // step 4: prefetch next head's chunk (flies across attn phase); QKV->LDS
    if (head < 5) ISSUE_QKV(head + 1);
    #pragma unroll
    for (int nt = 0; nt < 2; nt++){
      float bq = bqkv[      head * 32 + nt * 16 + l15];
      float bk = bqkv[192 + head * 32 + nt * 16 + l15];
      float bv = bqkv[384 + head * 32 + nt * 16 + l15];
      #pragma unroll
      for (int r = 0; r < 4; r++){
        Ql[(qrow + r) * 40 + nt * 16 + l15] = f2bf(acc[0][nt][r] + bq);
        Kl[(qrow + r) * 40 + nt * 16 + l15] = f2bf(acc[1][nt][r] + bk);
        Vt[(nt * 16 + l15) * 72 + qrow + r] = f2bf(acc[2][nt][r] + bv);
      }
    }
    // step 5: K/V visible cross-wave
    asm volatile("s_waitcnt lgkmcnt(0)\ns_barrier" ::: "memory");

    // step 6: S = Q K^T (hd=32 == one k-step)
    short8 aq = *(const short8*)&Ql[(w * 16 + l15) * 40 + quad * 8];
    f32x4 sa[4];
    #pragma unroll
    for (int kt = 0; kt < 4; kt++){
      short8 bk8 = *(const short8*)&Kl[(kt * 16 + l15) * 40 + quad * 8];
      sa[kt] = __builtin_amdgcn_mfma_f32_16x16x32_bf16(aq, bk8, (f32x4){0.f,0.f,0.f,0.f}, 0, 0, 0);
    }
    const float scale = 0.17677669529663687f;  // 32^-0.5
    float inv[4];
    #pragma unroll
    for (int r = 0; r < 4; r++){
      float s0 = sa[0][r] * scale, s1 = sa[1][r] * scale;
      float s2 = sa[2][r] * scale, s3 = sa[3][r] * scale;
      float mx = fmaxf(fmaxf(s0, s1), fmaxf(s2, s3));
      mx = fmaxf(mx, __shfl_xor(mx, 1)); mx = fmaxf(mx, __shfl_xor(mx, 2));
      mx = fmaxf(mx, __shfl_xor(mx, 4)); mx = fmaxf(mx, __shfl_xor(mx, 8));
      float p0 = __expf(s0 - mx), p1 = __expf(s1 - mx);
      float p2 = __expf(s2 - mx), p3 = __expf(s3 - mx);
      float l = p0 + p1 + p2 + p3;
      l += __shfl_xor(l, 1); l += __shfl_xor(l, 2);
      l += __shfl_xor(l, 4); l += __shfl_xor(l, 8);
      inv[r] = 1.f / l;
      Pl[(qrow + r) * 72 +      l15] = f2bf(p0);
      Pl[(qrow + r) * 72 + 16 + l15] = f2bf(p1);
      Pl[(qrow + r) * 72 + 32 + l15] = f2bf(p2);
      Pl[(qrow + r) * 72 + 48 + l15] = f2bf(p3);
    }
    // O = P V  (Pl rows wave-private; Vt barrier already passed)
    f32x4 oa[2];
    oa[0] = (f32x4){0.f,0.f,0.f,0.f}; oa[1] = (f32x4){0.f,0.f,0.f,0.f};
    #pragma unroll
    for (int ks = 0; ks < 2; ks++){
      short8 ap = *(const short8*)&Pl[(w * 16 + l15) * 72 + ks * 32 + quad * 8];
      #pragma unroll
      for (int nt = 0; nt < 2; nt++){
        short8 bv8 = *(const short8*)&Vt[(nt * 16 + l15) * 72 + ks * 32 + quad * 8];
        oa[nt] = __builtin_amdgcn_mfma_f32_16x16x32_bf16(ap, bv8, oa[nt], 0, 0, 0);
      }
    }
    #pragma unroll
    for (int nt = 0; nt < 2; nt++)
      #pragma unroll
      for (int r = 0; r < 4; r++)
        oall[head][nt][r] = oa[nt][r] * inv[r];
  }

  // all attn-buffer readers done before O stash overwrites the region
  asm volatile("s_waitcnt lgkmcnt(0)\ns_barrier" ::: "memory");

  // stash O (64x192, bf16) into hw (rows wave-private)
  #pragma unroll
  for (int h = 0; h < 6; h++)
    #pragma unroll
    for (int nt = 0; nt < 2; nt++)
      #pragma unroll
      for (int r = 0; r < 4; r++)
        hw[(qrow + r) * 200 + h * 32 + nt * 16 + l15] = f2bf(oall[h][nt][r]);

  // proj: xo = x + O @ w_proj + b_proj  (B-frags streamed from L2-resident wprojT)
  f32x4 accP[12];
  #pragma unroll
  for (int nt = 0; nt < 12; nt++) accP[nt] = (f32x4){0.f,0.f,0.f,0.f};
  #pragma unroll
  for (int k = 0; k < 6; k++){
    short8 af = *(const short8*)&hw[(w * 16 + l15) * 200 + k * 32 + quad * 8];
    #pragma unroll
    for (int nt = 0; nt < 12; nt++){
      short8 bfv = *(const short8*)(wprojT + (size_t)(nt * 16 + l15) * 192 + k * 32 + quad * 8);
      accP[nt] = __builtin_amdgcn_mfma_f32_16x16x32_bf16(af, bfv, accP[nt], 0, 0, 0);
    }
  }
  #pragma unroll
  for (int r = 0; r < 4; r++){
    int nn = qrow + r;
    int hr = hy * 8 + (nn >> 3), wcc = wx * 8 + (nn & 7);
    size_t tg = ((size_t)(b * 256 + hr)) * 256 + wcc;
    #pragma unroll
    for (int nt = 0; nt < 12; nt++){
      int col = nt * 16 + l15;
      size_t idx = tg * 192 + col;
      out[idx] = accP[nt][r] + bproj[col] + x[idx];
    }
  }
  #undef ISSUE_QKV
}

// ---------------- K2: fused LN2 + fc1 + GELU + fc2 + residual (in-place on io)
// v11: v9 pipeline at 2x the tokens per block. 2048 blocks x 512 threads
// (8 waves), 128 tokens/block. Same per-wave tiles as v9; weight staging,
// L2 traffic, and barriers per token HALVE; occupancy 2 blocks/CU = 16
// waves/CU (2x v9). LDS 77 KB: h2t[128][200] aliases BOTH w1 buffers;
// Ut[128][72] aliases w1s[cur]. Counted vmcnt re-derived for 8-wave split
// (per-wave >=3 items per batch).
__global__ __launch_bounds__(512, 4) void mlp_fused(
    const float* __restrict__ g2, const float* __restrict__ b2,
    const u16* __restrict__ wfc1P, const float* __restrict__ bfc1,
    const u16* __restrict__ wfc2P, const float* __restrict__ bfc2,
    float* __restrict__ io)
{
  __shared__ u16 w1s[2][64 * 200];  // 2 x 25.6 KB fc1 dbuf; h2t[128][200] = both; Ut aliases w1s[cur]
  __shared__ u16 w2s[192 * 72];     // 27.6 KB fc2 chunk
  u16* h2t = &w1s[0][0];            // 128*200 u16 spans both buffers (transient)

  const int tid = threadIdx.x, lane = tid & 63, w = tid >> 6;   // w in 0..7
  const int l15 = lane & 15, quad = lane >> 4;
  const int l31 = lane & 31, half = lane >> 5;
  const int wm = w >> 1, wn = w & 1;                            // 4 x 2 wave grid (fc2)
  const int t0 = blockIdx.x * 128;

  typedef const __attribute__((address_space(1))) void gv_t;
  typedef __attribute__((address_space(3))) void lv_t;

  // wave w stages items j = w, w+8, ... (1 KB per item). W1: 25 items, W2: 27.
  #define ISSUE_W1(ch, buf)                                                        \
    { const u16* src = wfc1P + (size_t)(ch) * 12800;                               \
      _Pragma("unroll")                                                            \
      for (int t = 0; t < 4; ++t){ int j = w + t * 8;                              \
        if (j < 25)                                                                \
          __builtin_amdgcn_global_load_lds((gv_t*)(src + j * 512 + lane * 8),      \
                                           (lv_t*)&w1s[buf][j * 512], 16, 0, 0); } }
  #define ISSUE_W2(ch)                                                             \
    { const u16* src = wfc2P + (size_t)(ch) * 13824;                               \
      _Pragma("unroll")                                                            \
      for (int t = 0; t < 4; ++t){ int j = w + t * 8;                              \
        if (j < 27)                                                                \
          __builtin_amdgcn_global_load_lds((gv_t*)(src + j * 512 + lane * 8),      \
                                           (lv_t*)&w2s[j * 512], 16, 0, 0); } }

  ISSUE_W2(0);   // w2s free during LN (h2t lives in w1s region) — flies under LN

  // ---- LN2 into h2t: 4 lanes per token, 16 tokens per wave (128 total) ----
  {
    int n = w * 16 + (lane >> 2), p = lane & 3;
    const float* xr = io + (size_t)(t0 + n) * 192 + p * 48;
    float v[48];
    #pragma unroll
    for (int c = 0; c < 12; c++) *(float4*)(v + c * 4) = *(const float4*)(xr + c * 4);
    float s = 0.f, ss = 0.f;
    #pragma unroll
    for (int i = 0; i < 48; i++){ s += v[i]; ss += v[i] * v[i]; }
    s += __shfl_xor(s, 1); ss += __shfl_xor(ss, 1);
    s += __shfl_xor(s, 2); ss += __shfl_xor(ss, 2);
    float m  = s * (1.f / 192.f);
    float rs = rsqrtf(ss * (1.f / 192.f) - m * m + 1e-5f);
    #pragma unroll
    for (int c = 0; c < 12; c++){
      float4 gv = *(const float4*)(g2 + p * 48 + c * 4);
      float4 bv = *(const float4*)(b2 + p * 48 + c * 4);
      short4v t;
      t.x = (short)f2bf((v[c*4+0] - m) * rs * gv.x + bv.x);
      t.y = (short)f2bf((v[c*4+1] - m) * rs * gv.y + bv.y);
      t.z = (short)f2bf((v[c*4+2] - m) * rs * gv.z + bv.z);
      t.w = (short)f2bf((v[c*4+3] - m) * rs * gv.w + bv.w);
      *(short4v*)&h2t[n * 200 + p * 48 + c * 4] = t;
    }
  }
  // afr rows are this wave's own LN rows (same-wave write->read); lgkm orders it
  asm volatile("s_waitcnt lgkmcnt(0)" ::: "memory");

  // ---- fc1 A-fragments to regs: wave's 16 tokens, 6 k-steps (24 VGPR) ----
  short8 afr[6];
  #pragma unroll
  for (int k = 0; k < 6; ++k)
    afr[k] = *(const short8*)&h2t[(w * 16 + l15) * 200 + k * 32 + quad * 8];
  asm volatile("s_waitcnt lgkmcnt(0)\ns_barrier" ::: "memory");   // all afr done; h2t dead

  // stage W1[0], W1[1] into the (now free) w1 buffers
  ISSUE_W1(0, 0);
  ISSUE_W1(1, 1);

  f32x16 accO[3];
  #pragma unroll
  for (int t = 0; t < 3; ++t)
    #pragma unroll
    for (int i = 0; i < 16; ++i) accO[t][i] = 0.f;

  #pragma unroll
  for (int ch = 0; ch < 12; ++ch){
    const int cur = ch & 1;
    // top wait: W1[ch] done. newer = (ch==0: W1[1]>=3) (steady: W2[ch]+W1[ch+1]>=6)
    // (ch==11: W2[11]>=3)
    if (ch == 0)      asm volatile("s_waitcnt vmcnt(3) lgkmcnt(0)\ns_barrier" ::: "memory");
    else if (ch < 11) asm volatile("s_waitcnt vmcnt(6) lgkmcnt(0)\ns_barrier" ::: "memory");
    else              asm volatile("s_waitcnt vmcnt(3) lgkmcnt(0)\ns_barrier" ::: "memory");

    // fc1: 16x16, wave = 16 tokens x 64 chunk-cols, K=192 (A from regs)
    f32x4 au[4];
    #pragma unroll
    for (int nt = 0; nt < 4; ++nt) au[nt] = (f32x4){0.f,0.f,0.f,0.f};
    #pragma unroll
    for (int k = 0; k < 6; ++k)
      #pragma unroll
      for (int nt = 0; nt < 4; ++nt){
        short8 bf = *(const short8*)&w1s[cur][(nt * 16 + l15) * 200 + k * 32 + quad * 8];
        au[nt] = __builtin_amdgcn_mfma_f32_16x16x32_bf16(afr[k], bf, au[nt], 0, 0, 0);
      }
    asm volatile("s_waitcnt lgkmcnt(0)\ns_barrier" ::: "memory");  // w1s[cur] reads done

    // bias + GELU -> Ut (aliases w1s[cur], [128][72])
    u16* Ut = &w1s[cur][0];
    #pragma unroll
    for (int nt = 0; nt < 4; ++nt){
      float bb = bfc1[ch * 64 + nt * 16 + l15];
      #pragma unroll
      for (int r = 0; r < 4; ++r)
        Ut[(w * 16 + quad * 4 + r) * 72 + nt * 16 + l15] = f2bf(gelu_fast(au[nt][r] + bb));
    }
    // Ut visible + W2[ch] arrived (newer = W1[ch+1] >= 3; last chunk: none)
    if (ch < 11) asm volatile("s_waitcnt vmcnt(3) lgkmcnt(0)\ns_barrier" ::: "memory");
    else         asm volatile("s_waitcnt vmcnt(0) lgkmcnt(0)\ns_barrier" ::: "memory");

    // fc2: 32x32, wave tile 32 tok x 96 outcols, K=64 (4x2 wave grid)
    #pragma unroll
    for (int ks = 0; ks < 4; ++ks){
      short8 uf = *(const short8*)&Ut[(wm * 32 + l31) * 72 + ks * 16 + half * 8];
      #pragma unroll
      for (int t = 0; t < 3; ++t){
        short8 bf = *(const short8*)&w2s[(wn * 96 + t * 32 + l31) * 72 + ks * 16 + half * 8];
        accO[t] = __builtin_amdgcn_mfma_f32_32x32x16_bf16(uf, bf, accO[t], 0, 0, 0);
      }
    }
    asm volatile("s_waitcnt lgkmcnt(0)\ns_barrier" ::: "memory");  // w2s & Ut reads done

    // stage ahead: W2[ch+1] into w2s (now free), W1[ch+2] into w1s[cur] (Ut dead)
    if (ch < 11) ISSUE_W2(ch + 1);
    if (ch < 10) ISSUE_W1(ch + 2, cur);
  }

  // epilogue: out = xo + (accO + b_fc2), in place (block-disjoint rows)
  #pragma unroll
  for (int t = 0; t < 3; ++t){
    int col = wn * 96 + t * 32 + l31;
    float bbo = bfc2[col];
    #pragma unroll
    for (int r = 0; r < 16; ++r){
      int row = t0 + wm * 32 + (r & 3) + 8 * (r >> 2) + 4 * half;
      size_t idx = (size_t)row * 192 + col;
      io[idx] = accO[t][r] + bbo + io[idx];
    }
  }
  #undef ISSUE_W1
  #undef ISSUE_W2
}

// ------------------------------------------------------------------------
extern "C" void kernel_launch(void* const* d_in, const int* in_sizes, int n_in,
                              void* d_out, int out_size, void* d_ws, size_t ws_size,
                              hipStream_t stream) {
  const float* x      = (const float*)d_in[0];
  const float* g1     = (const float*)d_in[1];
  const float* b1     = (const float*)d_in[2];
  const float* w_qkv  = (const float*)d_in[3];
  const float* b_qkv  = (const float*)d_in[4];
  const float* w_proj = (const float*)d_in[5];
  const float* b_proj = (const float*)d_in[6];
  const float* g2     = (const float*)d_in[7];
  const float* b2     = (const float*)d_in[8];
  const float* w_fc1  = (const float*)d_in[9];
  const float* b_fc1  = (const float*)d_in[10];
  const float* w_fc2  = (const float*)d_in[11];
  const float* b_fc2  = (const float*)d_in[12];
  float* out = (float*)d_out;

  // workspace: transposed bf16 weights (<1 MB)
  u16* wqkvP  = (u16*)d_ws;                      // 6 x (96x200+pad) = 116736 u16
  u16* wprojT = wqkvP  + 6 * 19456;              // 192x192
  u16* wfc1P  = wprojT + 192 * 192;              // 12 x (64x200)  chunk-contiguous
  u16* wfc2P  = wfc1P  + 12 * 12800;             // 12 x (192x72)  chunk-contiguous

  transpose_all<<<dim3(576, 4), 256, 0, stream>>>(w_qkv, wqkvP, w_proj, wprojT,
                                                  w_fc1, wfc1P, w_fc2, wfc2P);
  // d_out = x + attn(LN1(x)) @ w_proj + b_proj   (window-fused)
  win_attn<<<4096, 256, 0, stream>>>(x, g1, b1, wqkvP, b_qkv, wprojT, b_proj, out);
  // d_out += gelu(LN2(d_out) @ w_fc1 + b_fc1) @ w_fc2 + b_fc2   (in place)
  mlp_fused<<<2048, 512, 0, stream>>>(g2, b2, wfc1P, b_fc1, wfc2P, b_fc2, out);
}